// Round 5
// baseline (327.366 us; speedup 1.0000x reference)
//
#include <hip/hip_runtime.h>
#include <cstdint>

#define C_DIM 512
#define T_DIM 400
#define KW 31
#define TOUT 400
#define WSROW 432        // padded time index t+k in [0,430] -> 432
#define TPB 512
#define PPB 128          // (c,t) pairs per block; 4 k-split lanes each
#define ROWB 48          // LUT row stride in bytes (12 floats)

#define WSQ_BYTES (C_DIM * WSROW * 8)            // 1,769,472
#define RT_OFF    WSQ_BYTES
#define RT_BYTES  ((C_DIM * KW + 1) * 16)        // +1 slack row for prefetch
#define WS_NEEDED (WSQ_BYTES + RT_BYTES)

typedef float f2 __attribute__((ext_vector_type(2)));

// ---------------- host threefry2x32 (key-chain computation, pure CPU) --------
static inline uint32_t h_rotl32(uint32_t x, int d){ return (x<<d)|(x>>(32-d)); }

static void h_threefry2x32(uint32_t k0, uint32_t k1, uint32_t x0, uint32_t x1,
                           uint32_t* o0, uint32_t* o1){
  uint32_t ks2 = k0 ^ k1 ^ 0x1BD11BDAu;
  uint32_t ks[3] = {k0, k1, ks2};
  const int rotA[4] = {13,15,26,6};
  const int rotB[4] = {17,29,16,24};
  uint32_t v0 = x0 + k0, v1 = x1 + k1;
  for (int r = 0; r < 5; ++r){
    const int* rot = (r & 1) ? rotB : rotA;
    for (int q = 0; q < 4; ++q){
      v0 += v1; v1 = h_rotl32(v1, rot[q]); v1 ^= v0;
    }
    v0 += ks[(r+1)%3];
    v1 += ks[(r+2)%3] + (uint32_t)(r+1);
  }
  *o0 = v0; *o1 = v1;
}

// ---------------- device threefry, 4 independent streams in lockstep --------
template<int R>
__device__ __forceinline__ void tfr4(uint32_t v0[4], uint32_t v1[4]){
  #pragma unroll
  for (int n = 0; n < 4; ++n){
    v0[n] += v1[n];
    v1[n] = (v1[n] << R) | (v1[n] >> (32 - R));   // -> v_alignbit_b32
    v1[n] ^= v0[n];
  }
}

__device__ __forceinline__ void tfinj4(uint32_t v0[4], uint32_t v1[4],
                                       const uint32_t a[4], const uint32_t b[4],
                                       uint32_t cadd){
  #pragma unroll
  for (int n = 0; n < 4; ++n){ v0[n] += a[n]; v1[n] += b[n] + cadd; }
}

__device__ __forceinline__ void threefry_xor4(const uint32_t ka[4], const uint32_t kb[4],
                                              uint32_t j, uint32_t out[4]){
  uint32_t ks2[4], v0[4], v1[4];
  #pragma unroll
  for (int n = 0; n < 4; ++n){
    ks2[n] = ka[n] ^ kb[n] ^ 0x1BD11BDAu;
    v0[n] = ka[n];            // x0 = 0
    v1[n] = j + kb[n];        // x1 = j
  }
  tfr4<13>(v0,v1); tfr4<15>(v0,v1); tfr4<26>(v0,v1); tfr4<6>(v0,v1);
  tfinj4(v0,v1,kb,ks2,1u);
  tfr4<17>(v0,v1); tfr4<29>(v0,v1); tfr4<16>(v0,v1); tfr4<24>(v0,v1);
  tfinj4(v0,v1,ks2,ka,2u);
  tfr4<13>(v0,v1); tfr4<15>(v0,v1); tfr4<26>(v0,v1); tfr4<6>(v0,v1);
  tfinj4(v0,v1,ka,kb,3u);
  tfr4<17>(v0,v1); tfr4<29>(v0,v1); tfr4<16>(v0,v1); tfr4<24>(v0,v1);
  tfinj4(v0,v1,kb,ks2,4u);
  tfr4<13>(v0,v1); tfr4<15>(v0,v1); tfr4<26>(v0,v1); tfr4<6>(v0,v1);
  tfinj4(v0,v1,ks2,ka,5u);
  #pragma unroll
  for (int n = 0; n < 4; ++n) out[n] = v0[n] ^ v1[n];
}

// high-branch (rare) scalar erfinv tail: returns p such that erfinv = p*x
__device__ __forceinline__ float erfinv_hi(float w){
  float ws = __builtin_amdgcn_sqrtf(w) - 3.0f;
  float p =             -0.000200214257f;
  p = fmaf(p, ws,   0.000100950558f);
  p = fmaf(p, ws,   0.00134934322f);
  p = fmaf(p, ws,  -0.00367342844f);
  p = fmaf(p, ws,   0.00573950773f);
  p = fmaf(p, ws,  -0.0076224613f);
  p = fmaf(p, ws,   0.00943887047f);
  p = fmaf(p, ws,   1.00167406f);
  p = fmaf(p, ws,   2.83297682f);
  return p;
}

// ------- pre-pass 1: DAC-quantize x once per (c,time), store LDS byte offs --
__global__ __launch_bounds__(256) void dac_prepass(
    const float* __restrict__ x, uint2* __restrict__ wsq)
{
  const int m = blockIdx.x * 256 + threadIdx.x;      // exact over C_DIM*WSROW
  const int c  = m / WSROW;
  const int tp = m - c * WSROW;
  const int time = tp - 15;
  const bool inb = (time >= 0) && (time < T_DIM);
  uint32_t off[4];
  #pragma unroll
  for (int b = 0; b < 4; ++b){
    float xv = inb ? x[(b * C_DIM + c) * T_DIM + time] : 0.0f;
    float q = rintf(xv * 128.0f);
    q = fminf(fmaxf(q, -128.0f), 128.0f);
    off[b] = (uint32_t)(((int)q + 128) * ROWB);      // LDS byte offset
  }
  wsq[m] = make_uint2(off[0] | (off[1] << 16), off[2] | (off[3] << 16));
}

// ------- pre-pass 2: transpose r to (c, k, is) float4 -----------------------
__global__ __launch_bounds__(256) void r_prepass(
    const float* __restrict__ r, float4* __restrict__ rT)
{
  const int m = blockIdx.x * 256 + threadIdx.x;      // over C_DIM*KW
  if (m >= C_DIM * KW) return;
  const int c = m / KW;
  const int k = m - c * KW;
  float4 v;
  v.x = r[(0 * C_DIM + c) * KW + k];
  v.y = r[(1 * C_DIM + c) * KW + k];
  v.z = r[(2 * C_DIM + c) * KW + k];
  v.w = r[(3 * C_DIM + c) * KW + k];
  rT[m] = v;
}

// ---------------- main kernel ----------------------------------------------
template<bool USE_WS>
__global__ __launch_bounds__(TPB, 4) void memristor_main(
    const float* __restrict__ x,
    const float* __restrict__ poly_low,   // (2,2,7)
    const float* __restrict__ poly_high,  // (2,2,6)
    const float* __restrict__ r,          // (2,2,C,K)
    const float* __restrict__ bias,
    const uint2* __restrict__ wsq,        // (C, WSROW) packed u16 byte-offs x4
    const float4* __restrict__ rT,        // (C, K) -> (r0,r1,r2,r3)
    float* __restrict__ out,              // (B,C,TOUT)
    uint32_t nk0a, uint32_t nk0b, uint32_t nk1a, uint32_t nk1b,
    uint32_t nk2a, uint32_t nk2b, uint32_t nk3a, uint32_t nk3b)
{
  // row = 12 floats: [lo0,lo1,d0,d1, lo2,lo3,d2,d3, sj*sqrt2, pad x3]
  __shared__ __align__(16) float lut[257 * 12];

  const int tid = threadIdx.x;

  if (tid < 257){
    const int qi = tid;
    const float q = (float)(qi - 128);
    const float w = (q * 0.0078125f) * 0.6f;
    float lov[4], div[4];
    #pragma unroll
    for (int is = 0; is < 4; ++is){
      const float* pl = poly_low  + is * 7;
      const float* ph = poly_high + is * 6;
      float lo = pl[6];
      lo = fmaf(lo, w, pl[5]); lo = fmaf(lo, w, pl[4]); lo = fmaf(lo, w, pl[3]);
      lo = fmaf(lo, w, pl[2]); lo = fmaf(lo, w, pl[1]); lo = fmaf(lo, w, pl[0]);
      float hi = ph[5];
      hi = fmaf(hi, w, ph[4]); hi = fmaf(hi, w, ph[3]); hi = fmaf(hi, w, ph[2]);
      hi = fmaf(hi, w, ph[1]); hi = fmaf(hi, w, ph[0]);
      lov[is] = lo; div[is] = hi - lo;
    }
    lut[qi*12 + 0] = lov[0]; lut[qi*12 + 1] = lov[1];
    lut[qi*12 + 2] = div[0]; lut[qi*12 + 3] = div[1];
    lut[qi*12 + 4] = lov[2]; lut[qi*12 + 5] = lov[3];
    lut[qi*12 + 6] = div[2]; lut[qi*12 + 7] = div[3];
    const float jf = fmaf(1.6567788e-28f,
                          __builtin_amdgcn_rcpf(fabsf(w) + 1e-12f),
                          5.4365637e-08f);
    lut[qi*12 + 8] = __builtin_amdgcn_sqrtf(jf) * 1.41421356f; // sqrt2 folded
  }
  __syncthreads();

  // 4 lanes per (c,t): lane l covers k in [8l, min(8l+8, 31))
  const int l   = tid & 3;
  const int p   = tid >> 2;
  const int gid = blockIdx.x * PPB + p;     // exact: grid*PPB == C*TOUT
  const int c   = gid / TOUT;
  const int t   = gid - c * TOUT;
  const int k0  = l * 8;

  const uint32_t ka[4] = {nk0a, nk1a, nk2a, nk3a};
  const uint32_t kb[4] = {nk0b, nk1b, nk2b, nk3b};
  const uint32_t jbase = (uint32_t)((t * C_DIM + c) * KW) + (uint32_t)k0;

  // ---- prefetch all 8 k-iterations' data into registers ----
  uint2  wv[8];
  float4 rv[8];
  if (USE_WS){
    const uint2*  wp = wsq + c * WSROW + t + k0;
    const float4* rp = rT + c * KW + k0;
    #pragma unroll
    for (int kk = 0; kk < 8; ++kk){ wv[kk] = wp[kk]; rv[kk] = rp[kk]; }
  } else {
    #pragma unroll
    for (int kk = 0; kk < 8; ++kk){
      const int k = k0 + kk;
      const int time = t + k - 15;
      const bool inb = (time >= 0) && (time < T_DIM) && (k < KW);
      uint32_t off[4];
      #pragma unroll
      for (int b = 0; b < 4; ++b){
        float xv = inb ? x[(b * C_DIM + c) * T_DIM + time] : 0.0f;
        float q = rintf(xv * 128.0f);
        q = fminf(fmaxf(q, -128.0f), 128.0f);
        off[b] = (uint32_t)(((int)q + 128) * ROWB);
      }
      wv[kk] = make_uint2(off[0] | (off[1] << 16), off[2] | (off[3] << 16));
      const int kc = (k < KW) ? k : 0;
      rv[kk].x = r[(0 * C_DIM + c) * KW + kc];
      rv[kk].y = r[(1 * C_DIM + c) * KW + kc];
      rv[kk].z = r[(2 * C_DIM + c) * KW + kc];
      rv[kk].w = r[(3 * C_DIM + c) * KW + kc];
    }
  }

  f2 acc01[4], acc23[4];                    // [b], packed over is-pairs
  #pragma unroll
  for (int b = 0; b < 4; ++b){ acc01[b] = (f2)(0.0f); acc23[b] = (f2)(0.0f); }

  auto body = [&](int kk){
    const uint2 ld = wv[kk];
    uint32_t off[4];
    off[0] = ld.x & 0xFFFFu; off[1] = ld.x >> 16;
    off[2] = ld.y & 0xFFFFu; off[3] = ld.y >> 16;
    const f2 rr01 = {rv[kk].x, rv[kk].y};
    const f2 rr23 = {rv[kk].z, rv[kk].w};

    uint32_t bits[4];
    threefry_xor4(ka, kb, jbase + (uint32_t)kk, bits);

    // packed u -> x, (1-x)(1+x)
    const f2 u01 = { __uint_as_float((bits[0] >> 9) | 0x3f800000u),
                     __uint_as_float((bits[1] >> 9) | 0x3f800000u) };
    const f2 u23 = { __uint_as_float((bits[2] >> 9) | 0x3f800000u),
                     __uint_as_float((bits[3] >> 9) | 0x3f800000u) };
    // u1 = u - 1 in [0,1); x = 2*u1 + LO (clamp provably identity)
    const float LO = -0.99999994f;
    const f2 u1_01 = u01 - 1.0f, u1_23 = u23 - 1.0f;
    const f2 x01 = u1_01 * 2.0f + LO;
    const f2 x23 = u1_23 * 2.0f + LO;
    const f2 a01 = u1_01 * (-2.0f) + 1.99999994f;   // 1-x
    const f2 a23 = u1_23 * (-2.0f) + 1.99999994f;
    const f2 b01 = u1_01 * 2.0f + 5.9604645e-8f;    // 1+x
    const f2 b23 = u1_23 * 2.0f + 5.9604645e-8f;
    const f2 pr01 = a01 * b01, pr23 = a23 * b23;

    const f2 w01 = { __builtin_amdgcn_logf(pr01.x) * (-0.69314718f),
                     __builtin_amdgcn_logf(pr01.y) * (-0.69314718f) };
    const f2 w23 = { __builtin_amdgcn_logf(pr23.x) * (-0.69314718f),
                     __builtin_amdgcn_logf(pr23.y) * (-0.69314718f) };

    // packed low-branch poly (valid for w < 5; fixups below)
    const f2 t01 = w01 - 2.5f, t23 = w23 - 2.5f;
    f2 p01 = (f2)(2.81022636e-08f), p23 = (f2)(2.81022636e-08f);
    p01 = p01*t01 + 3.43273939e-07f;  p23 = p23*t23 + 3.43273939e-07f;
    p01 = p01*t01 + -3.5233877e-06f;  p23 = p23*t23 + -3.5233877e-06f;
    p01 = p01*t01 + -4.39150654e-06f; p23 = p23*t23 + -4.39150654e-06f;
    p01 = p01*t01 + 0.00021858087f;   p23 = p23*t23 + 0.00021858087f;
    p01 = p01*t01 + -0.00125372503f;  p23 = p23*t23 + -0.00125372503f;
    p01 = p01*t01 + -0.00417768164f;  p23 = p23*t23 + -0.00417768164f;
    p01 = p01*t01 + 0.246640727f;     p23 = p23*t23 + 0.246640727f;
    p01 = p01*t01 + 1.50140941f;      p23 = p23*t23 + 1.50140941f;

    // rare tail fixups (p(any lane) ~ 19% per stream)
    if (w01.x >= 5.0f) p01.x = erfinv_hi(w01.x);
    if (w01.y >= 5.0f) p01.y = erfinv_hi(w01.y);
    if (w23.x >= 5.0f) p23.x = erfinv_hi(w23.x);
    if (w23.y >= 5.0f) p23.y = erfinv_hi(w23.y);

    const f2 noise01 = p01 * x01;     // sqrt2 folded into LUT sj
    const f2 noise23 = p23 * x23;

    #pragma unroll
    for (int b = 0; b < 4; ++b){
      const float* row = (const float*)((const char*)lut + off[b]);
      const float4 A  = *(const float4*)(row);      // lo0,lo1,d0,d1
      const float4 Bv = *(const float4*)(row + 4);  // lo2,lo3,d2,d3
      const float sj  = row[8];
      const f2 lo01 = {A.x, A.y},  d01 = {A.z, A.w};
      const f2 lo23 = {Bv.x, Bv.y}, d23 = {Bv.z, Bv.w};
      const f2 raw01 = d01 * rr01 + lo01;           // pk_fma
      const f2 raw23 = d23 * rr23 + lo23;
      const f2 s01 = { __builtin_amdgcn_sqrtf(fabsf(raw01.x)),
                       __builtin_amdgcn_sqrtf(fabsf(raw01.y)) };
      const f2 s23 = { __builtin_amdgcn_sqrtf(fabsf(raw23.x)),
                       __builtin_amdgcn_sqrtf(fabsf(raw23.y)) };
      const f2 nsj01 = noise01 * sj;
      const f2 nsj23 = noise23 * sj;
      acc01[b] = nsj01 * s01 + (acc01[b] + raw01);
      acc23[b] = nsj23 * s23 + (acc23[b] + raw23);
    }
  };

  #pragma unroll
  for (int kk = 0; kk < 7; ++kk) body(kk);
  if (l != 3) body(7);                      // k=31 doesn't exist

  // quad butterfly combine: every lane ends with full sums
  if ((p & 0) == 0) {}                      // (no-op, keep structure clear)
  const float bv = bias[c];
  float o[4];
  #pragma unroll
  for (int b = 0; b < 4; ++b){
    f2 t01 = acc01[b], t23 = acc23[b];
    t01.x += __shfl_xor(t01.x, 1); t01.x += __shfl_xor(t01.x, 2);
    t01.y += __shfl_xor(t01.y, 1); t01.y += __shfl_xor(t01.y, 2);
    t23.x += __shfl_xor(t23.x, 1); t23.x += __shfl_xor(t23.x, 2);
    t23.y += __shfl_xor(t23.y, 1); t23.y += __shfl_xor(t23.y, 2);
    float oo = 0.0f;
    {
      const float pair = t01.x - t01.y;     // i=0, weight 2
      float q = rintf((pair * 8020.0f) * 256.0f);
      q = fminf(fmaxf(q, -131072.0f), 131072.0f);
      oo += (q * 0.00390625f) * 2.0f;
    }
    {
      const float pair = t23.x - t23.y;     // i=1, weight 1
      float q = rintf((pair * 8020.0f) * 256.0f);
      q = fminf(fmaxf(q, -131072.0f), 131072.0f);
      oo += (q * 0.00390625f);
    }
    o[b] = oo + bv;
  }
  if (l == 0){
    #pragma unroll
    for (int b = 0; b < 4; ++b)
      out[(b * C_DIM + c) * TOUT + t] = o[b];
  }
}

extern "C" void kernel_launch(void* const* d_in, const int* in_sizes, int n_in,
                              void* d_out, int out_size, void* d_ws, size_t ws_size,
                              hipStream_t stream) {
  const float* x         = (const float*)d_in[0];
  const float* poly_low  = (const float*)d_in[1];
  const float* poly_high = (const float*)d_in[2];
  const float* r         = (const float*)d_in[3];
  const float* bias      = (const float*)d_in[4];
  float* out             = (float*)d_out;

  // key chain: key = jax.random.key(42); 4x (key, nk) = split(key)
  uint32_t ck0 = 0u, ck1 = 42u;
  uint32_t nk[4][2];
  for (int n = 0; n < 4; ++n){
    uint32_t a0, a1, b0, b1;
    h_threefry2x32(ck0, ck1, 0u, 0u, &a0, &a1);  // new key
    h_threefry2x32(ck0, ck1, 0u, 1u, &b0, &b1);  // nk
    nk[n][0] = b0; nk[n][1] = b1;
    ck0 = a0; ck1 = a1;
  }

  const int nblocks = (C_DIM * TOUT) / PPB;      // 1600, exact

  if (ws_size >= (size_t)WS_NEEDED){
    uint2*  wsq = (uint2*)d_ws;
    float4* rT  = (float4*)((char*)d_ws + RT_OFF);
    hipLaunchKernelGGL(dac_prepass, dim3((C_DIM * WSROW) / 256), dim3(256),
                       0, stream, x, wsq);
    hipLaunchKernelGGL(r_prepass, dim3((C_DIM * KW + 255) / 256), dim3(256),
                       0, stream, r, rT);
    hipLaunchKernelGGL((memristor_main<true>), dim3(nblocks), dim3(TPB), 0, stream,
                       x, poly_low, poly_high, r, bias, wsq, rT, out,
                       nk[0][0], nk[0][1], nk[1][0], nk[1][1],
                       nk[2][0], nk[2][1], nk[3][0], nk[3][1]);
  } else {
    hipLaunchKernelGGL((memristor_main<false>), dim3(nblocks), dim3(TPB), 0, stream,
                       x, poly_low, poly_high, r, bias,
                       (const uint2*)nullptr, (const float4*)nullptr, out,
                       nk[0][0], nk[0][1], nk[1][0], nk[1][1],
                       nk[2][0], nk[2][1], nk[3][0], nk[3][1]);
  }
}

// Round 6
// 111.244 us; speedup vs baseline: 2.9428x; 2.9428x over previous
//
#include <hip/hip_runtime.h>
#include <cstdint>

#define C_DIM 512
#define T_DIM 400
#define KW 31
#define TOUT 400
#define WSROW 432        // padded time index t+k in [0,430] -> 432
#define TPB 512
#define PPB 128          // (c,t) pairs per block; 4 k-split lanes each
#define ROWB 48          // LUT row stride in bytes (12 floats)

#define WSQ_BYTES (C_DIM * WSROW * 8)            // 1,769,472
#define RT_OFF    WSQ_BYTES
#define RT_BYTES  (C_DIM * KW * 16)              // 253,952
#define WS_NEEDED (WSQ_BYTES + RT_BYTES)

typedef float f2 __attribute__((ext_vector_type(2)));

// ---------------- host threefry2x32 (key-chain computation, pure CPU) --------
static inline uint32_t h_rotl32(uint32_t x, int d){ return (x<<d)|(x>>(32-d)); }

static void h_threefry2x32(uint32_t k0, uint32_t k1, uint32_t x0, uint32_t x1,
                           uint32_t* o0, uint32_t* o1){
  uint32_t ks2 = k0 ^ k1 ^ 0x1BD11BDAu;
  uint32_t ks[3] = {k0, k1, ks2};
  const int rotA[4] = {13,15,26,6};
  const int rotB[4] = {17,29,16,24};
  uint32_t v0 = x0 + k0, v1 = x1 + k1;
  for (int r = 0; r < 5; ++r){
    const int* rot = (r & 1) ? rotB : rotA;
    for (int q = 0; q < 4; ++q){
      v0 += v1; v1 = h_rotl32(v1, rot[q]); v1 ^= v0;
    }
    v0 += ks[(r+1)%3];
    v1 += ks[(r+2)%3] + (uint32_t)(r+1);
  }
  *o0 = v0; *o1 = v1;
}

// ---------------- device threefry, 4 independent streams in lockstep --------
template<int R>
__device__ __forceinline__ void tfr4(uint32_t v0[4], uint32_t v1[4]){
  #pragma unroll
  for (int n = 0; n < 4; ++n){
    v0[n] += v1[n];
    v1[n] = (v1[n] << R) | (v1[n] >> (32 - R));   // -> v_alignbit_b32
    v1[n] ^= v0[n];
  }
}

__device__ __forceinline__ void tfinj4(uint32_t v0[4], uint32_t v1[4],
                                       const uint32_t a[4], const uint32_t b[4],
                                       uint32_t cadd){
  #pragma unroll
  for (int n = 0; n < 4; ++n){ v0[n] += a[n]; v1[n] += b[n] + cadd; }
}

__device__ __forceinline__ void threefry_xor4(const uint32_t ka[4], const uint32_t kb[4],
                                              uint32_t j, uint32_t out[4]){
  uint32_t ks2[4], v0[4], v1[4];
  #pragma unroll
  for (int n = 0; n < 4; ++n){
    ks2[n] = ka[n] ^ kb[n] ^ 0x1BD11BDAu;
    v0[n] = ka[n];            // x0 = 0
    v1[n] = j + kb[n];        // x1 = j
  }
  tfr4<13>(v0,v1); tfr4<15>(v0,v1); tfr4<26>(v0,v1); tfr4<6>(v0,v1);
  tfinj4(v0,v1,kb,ks2,1u);
  tfr4<17>(v0,v1); tfr4<29>(v0,v1); tfr4<16>(v0,v1); tfr4<24>(v0,v1);
  tfinj4(v0,v1,ks2,ka,2u);
  tfr4<13>(v0,v1); tfr4<15>(v0,v1); tfr4<26>(v0,v1); tfr4<6>(v0,v1);
  tfinj4(v0,v1,ka,kb,3u);
  tfr4<17>(v0,v1); tfr4<29>(v0,v1); tfr4<16>(v0,v1); tfr4<24>(v0,v1);
  tfinj4(v0,v1,kb,ks2,4u);
  tfr4<13>(v0,v1); tfr4<15>(v0,v1); tfr4<26>(v0,v1); tfr4<6>(v0,v1);
  tfinj4(v0,v1,ks2,ka,5u);
  #pragma unroll
  for (int n = 0; n < 4; ++n) out[n] = v0[n] ^ v1[n];
}

// high-branch (rare) scalar erfinv tail: returns p such that erfinv = p*x
__device__ __forceinline__ float erfinv_hi(float w){
  float ws = __builtin_amdgcn_sqrtf(w) - 3.0f;
  float p =             -0.000200214257f;
  p = fmaf(p, ws,   0.000100950558f);
  p = fmaf(p, ws,   0.00134934322f);
  p = fmaf(p, ws,  -0.00367342844f);
  p = fmaf(p, ws,   0.00573950773f);
  p = fmaf(p, ws,  -0.0076224613f);
  p = fmaf(p, ws,   0.00943887047f);
  p = fmaf(p, ws,   1.00167406f);
  p = fmaf(p, ws,   2.83297682f);
  return p;
}

// ------- pre-pass 1: DAC-quantize x once per (c,time), store LDS byte offs --
__global__ __launch_bounds__(256) void dac_prepass(
    const float* __restrict__ x, uint2* __restrict__ wsq)
{
  const int m = blockIdx.x * 256 + threadIdx.x;      // exact over C_DIM*WSROW
  const int c  = m / WSROW;
  const int tp = m - c * WSROW;
  const int time = tp - 15;
  const bool inb = (time >= 0) && (time < T_DIM);
  uint32_t off[4];
  #pragma unroll
  for (int b = 0; b < 4; ++b){
    float xv = inb ? x[(b * C_DIM + c) * T_DIM + time] : 0.0f;
    float q = rintf(xv * 128.0f);
    q = fminf(fmaxf(q, -128.0f), 128.0f);
    off[b] = (uint32_t)(((int)q + 128) * ROWB);      // LDS byte offset
  }
  wsq[m] = make_uint2(off[0] | (off[1] << 16), off[2] | (off[3] << 16));
}

// ------- pre-pass 2: transpose r to (c, k, is) float4 -----------------------
__global__ __launch_bounds__(256) void r_prepass(
    const float* __restrict__ r, float4* __restrict__ rT)
{
  const int m = blockIdx.x * 256 + threadIdx.x;      // over C_DIM*KW
  if (m >= C_DIM * KW) return;
  const int c = m / KW;
  const int k = m - c * KW;
  float4 v;
  v.x = r[(0 * C_DIM + c) * KW + k];
  v.y = r[(1 * C_DIM + c) * KW + k];
  v.z = r[(2 * C_DIM + c) * KW + k];
  v.w = r[(3 * C_DIM + c) * KW + k];
  rT[m] = v;
}

// ---------------- main kernel ----------------------------------------------
template<bool USE_WS>
__global__ __launch_bounds__(TPB) void memristor_main(
    const float* __restrict__ x,
    const float* __restrict__ poly_low,   // (2,2,7)
    const float* __restrict__ poly_high,  // (2,2,6)
    const float* __restrict__ r,          // (2,2,C,K)
    const float* __restrict__ bias,
    const uint2* __restrict__ wsq,        // (C, WSROW) packed u16 byte-offs x4
    const float4* __restrict__ rT,        // (C, K) -> (r0,r1,r2,r3)
    float* __restrict__ out,              // (B,C,TOUT)
    uint32_t nk0a, uint32_t nk0b, uint32_t nk1a, uint32_t nk1b,
    uint32_t nk2a, uint32_t nk2b, uint32_t nk3a, uint32_t nk3b)
{
  // row = 12 floats: [lo0,lo1,d0,d1, lo2,lo3,d2,d3, sj*sqrt2, pad x3]
  __shared__ __align__(16) float lut[257 * 12];

  const int tid = threadIdx.x;

  if (tid < 257){
    const int qi = tid;
    const float q = (float)(qi - 128);
    const float w = (q * 0.0078125f) * 0.6f;
    float lov[4], div[4];
    #pragma unroll
    for (int is = 0; is < 4; ++is){
      const float* pl = poly_low  + is * 7;
      const float* ph = poly_high + is * 6;
      float lo = pl[6];
      lo = fmaf(lo, w, pl[5]); lo = fmaf(lo, w, pl[4]); lo = fmaf(lo, w, pl[3]);
      lo = fmaf(lo, w, pl[2]); lo = fmaf(lo, w, pl[1]); lo = fmaf(lo, w, pl[0]);
      float hi = ph[5];
      hi = fmaf(hi, w, ph[4]); hi = fmaf(hi, w, ph[3]); hi = fmaf(hi, w, ph[2]);
      hi = fmaf(hi, w, ph[1]); hi = fmaf(hi, w, ph[0]);
      lov[is] = lo; div[is] = hi - lo;
    }
    lut[qi*12 + 0] = lov[0]; lut[qi*12 + 1] = lov[1];
    lut[qi*12 + 2] = div[0]; lut[qi*12 + 3] = div[1];
    lut[qi*12 + 4] = lov[2]; lut[qi*12 + 5] = lov[3];
    lut[qi*12 + 6] = div[2]; lut[qi*12 + 7] = div[3];
    const float jf = fmaf(1.6567788e-28f,
                          __builtin_amdgcn_rcpf(fabsf(w) + 1e-12f),
                          5.4365637e-08f);
    lut[qi*12 + 8] = __builtin_amdgcn_sqrtf(jf) * 1.41421356f; // sqrt2 folded
  }
  __syncthreads();

  // 4 lanes per (c,t): lane l covers k in [8l, min(8l+8, 31))
  const int l   = tid & 3;
  const int p   = tid >> 2;
  const int gid = blockIdx.x * PPB + p;     // exact: grid*PPB == C*TOUT
  const int c   = gid / TOUT;
  const int t   = gid - c * TOUT;
  const int k0  = l * 8;
  const int kn  = (l == 3) ? 7 : 8;

  const uint32_t ka[4] = {nk0a, nk1a, nk2a, nk3a};
  const uint32_t kb[4] = {nk0b, nk1b, nk2b, nk3b};
  const uint32_t jbase = (uint32_t)((t * C_DIM + c) * KW) + (uint32_t)k0;

  const uint2*  wp = USE_WS ? (wsq + c * WSROW + t + k0) : nullptr;
  const float4* rp = USE_WS ? (rT + c * KW + k0) : nullptr;

  f2 acc01[4], acc23[4];                    // [b], packed over is-pairs
  #pragma unroll
  for (int b = 0; b < 4; ++b){ acc01[b] = (f2)(0.0f); acc23[b] = (f2)(0.0f); }

  for (int kk = 0; kk < kn; ++kk){
    // ---- per-k loads (L2-resident, inline like R4 — no register arrays) ----
    uint32_t off0, off1, off2, off3;
    f2 rr01, rr23;
    if (USE_WS){
      const uint2  ld = wp[kk];
      const float4 rv = rp[kk];
      off0 = ld.x & 0xFFFFu; off1 = ld.x >> 16;
      off2 = ld.y & 0xFFFFu; off3 = ld.y >> 16;
      rr01 = (f2){rv.x, rv.y};
      rr23 = (f2){rv.z, rv.w};
    } else {
      const int k = k0 + kk;
      const int time = t + k - 15;
      const bool inb = (time >= 0) && (time < T_DIM);
      uint32_t off[4];
      #pragma unroll
      for (int b = 0; b < 4; ++b){
        float xv = inb ? x[(b * C_DIM + c) * T_DIM + time] : 0.0f;
        float q = rintf(xv * 128.0f);
        q = fminf(fmaxf(q, -128.0f), 128.0f);
        off[b] = (uint32_t)(((int)q + 128) * ROWB);
      }
      off0 = off[0]; off1 = off[1]; off2 = off[2]; off3 = off[3];
      rr01 = (f2){ r[(0 * C_DIM + c) * KW + k], r[(1 * C_DIM + c) * KW + k] };
      rr23 = (f2){ r[(2 * C_DIM + c) * KW + k], r[(3 * C_DIM + c) * KW + k] };
    }

    uint32_t bits[4];
    threefry_xor4(ka, kb, jbase + (uint32_t)kk, bits);

    // ---- packed u -> x, (1-x)(1+x) (math identical to validated R5) ----
    const f2 u01 = { __uint_as_float((bits[0] >> 9) | 0x3f800000u),
                     __uint_as_float((bits[1] >> 9) | 0x3f800000u) };
    const f2 u23 = { __uint_as_float((bits[2] >> 9) | 0x3f800000u),
                     __uint_as_float((bits[3] >> 9) | 0x3f800000u) };
    const float LO = -0.99999994f;
    const f2 u1_01 = u01 - 1.0f, u1_23 = u23 - 1.0f;
    const f2 x01 = u1_01 * 2.0f + LO;
    const f2 x23 = u1_23 * 2.0f + LO;
    const f2 a01 = u1_01 * (-2.0f) + 1.99999994f;   // 1-x
    const f2 a23 = u1_23 * (-2.0f) + 1.99999994f;
    const f2 b01 = u1_01 * 2.0f + 5.9604645e-8f;    // 1+x
    const f2 b23 = u1_23 * 2.0f + 5.9604645e-8f;
    const f2 pr01 = a01 * b01, pr23 = a23 * b23;

    // L = log2(pr); w = -ln2*L; poly arg t = w-2.5 = fma(L,-ln2,-2.5)
    const f2 L01 = { __builtin_amdgcn_logf(pr01.x),
                     __builtin_amdgcn_logf(pr01.y) };
    const f2 L23 = { __builtin_amdgcn_logf(pr23.x),
                     __builtin_amdgcn_logf(pr23.y) };
    const f2 t01 = L01 * (-0.69314718f) + (-2.5f);
    const f2 t23 = L23 * (-0.69314718f) + (-2.5f);

    f2 p01 = (f2)(2.81022636e-08f), p23 = (f2)(2.81022636e-08f);
    p01 = p01*t01 + 3.43273939e-07f;  p23 = p23*t23 + 3.43273939e-07f;
    p01 = p01*t01 + -3.5233877e-06f;  p23 = p23*t23 + -3.5233877e-06f;
    p01 = p01*t01 + -4.39150654e-06f; p23 = p23*t23 + -4.39150654e-06f;
    p01 = p01*t01 + 0.00021858087f;   p23 = p23*t23 + 0.00021858087f;
    p01 = p01*t01 + -0.00125372503f;  p23 = p23*t23 + -0.00125372503f;
    p01 = p01*t01 + -0.00417768164f;  p23 = p23*t23 + -0.00417768164f;
    p01 = p01*t01 + 0.246640727f;     p23 = p23*t23 + 0.246640727f;
    p01 = p01*t01 + 1.50140941f;      p23 = p23*t23 + 1.50140941f;

    // rare tail fixups: w >= 5  <=>  L <= -5/ln2
    const float LTH = -7.2134752f;
    if (L01.x <= LTH) p01.x = erfinv_hi(L01.x * -0.69314718f);
    if (L01.y <= LTH) p01.y = erfinv_hi(L01.y * -0.69314718f);
    if (L23.x <= LTH) p23.x = erfinv_hi(L23.x * -0.69314718f);
    if (L23.y <= LTH) p23.y = erfinv_hi(L23.y * -0.69314718f);

    const f2 noise01 = p01 * x01;     // sqrt2 folded into LUT sj
    const f2 noise23 = p23 * x23;

    #pragma unroll
    for (int b = 0; b < 4; ++b){
      const uint32_t off = (b == 0) ? off0 : (b == 1) ? off1 : (b == 2) ? off2 : off3;
      const float* row = (const float*)((const char*)lut + off);
      const float4 A  = *(const float4*)(row);      // lo0,lo1,d0,d1
      const float4 Bv = *(const float4*)(row + 4);  // lo2,lo3,d2,d3
      const float sj  = row[8];
      const f2 lo01 = {A.x, A.y},  d01 = {A.z, A.w};
      const f2 lo23 = {Bv.x, Bv.y}, d23 = {Bv.z, Bv.w};
      const f2 raw01 = d01 * rr01 + lo01;           // pk_fma
      const f2 raw23 = d23 * rr23 + lo23;
      const f2 s01 = { __builtin_amdgcn_sqrtf(fabsf(raw01.x)),
                       __builtin_amdgcn_sqrtf(fabsf(raw01.y)) };
      const f2 s23 = { __builtin_amdgcn_sqrtf(fabsf(raw23.x)),
                       __builtin_amdgcn_sqrtf(fabsf(raw23.y)) };
      const f2 nsj01 = noise01 * sj;
      const f2 nsj23 = noise23 * sj;
      acc01[b] = nsj01 * s01 + (acc01[b] + raw01);
      acc23[b] = nsj23 * s23 + (acc23[b] + raw23);
    }
  }

  // quad butterfly combine: every lane ends with full sums
  const float bv = bias[c];
  if (l == 0 || true){}   // all lanes participate in shuffles below
  #pragma unroll
  for (int b = 0; b < 4; ++b){
    f2 t01 = acc01[b], t23 = acc23[b];
    t01.x += __shfl_xor(t01.x, 1); t01.x += __shfl_xor(t01.x, 2);
    t01.y += __shfl_xor(t01.y, 1); t01.y += __shfl_xor(t01.y, 2);
    t23.x += __shfl_xor(t23.x, 1); t23.x += __shfl_xor(t23.x, 2);
    t23.y += __shfl_xor(t23.y, 1); t23.y += __shfl_xor(t23.y, 2);
    acc01[b] = t01; acc23[b] = t23;
  }

  if (l == 0){
    #pragma unroll
    for (int b = 0; b < 4; ++b){
      float oo = 0.0f;
      {
        const float pair = acc01[b].x - acc01[b].y;   // i=0, weight 2
        float q = rintf((pair * 8020.0f) * 256.0f);
        q = fminf(fmaxf(q, -131072.0f), 131072.0f);
        oo += (q * 0.00390625f) * 2.0f;
      }
      {
        const float pair = acc23[b].x - acc23[b].y;   // i=1, weight 1
        float q = rintf((pair * 8020.0f) * 256.0f);
        q = fminf(fmaxf(q, -131072.0f), 131072.0f);
        oo += (q * 0.00390625f);
      }
      out[(b * C_DIM + c) * TOUT + t] = oo + bv;
    }
  }
}

extern "C" void kernel_launch(void* const* d_in, const int* in_sizes, int n_in,
                              void* d_out, int out_size, void* d_ws, size_t ws_size,
                              hipStream_t stream) {
  const float* x         = (const float*)d_in[0];
  const float* poly_low  = (const float*)d_in[1];
  const float* poly_high = (const float*)d_in[2];
  const float* r         = (const float*)d_in[3];
  const float* bias      = (const float*)d_in[4];
  float* out             = (float*)d_out;

  // key chain: key = jax.random.key(42); 4x (key, nk) = split(key)
  uint32_t ck0 = 0u, ck1 = 42u;
  uint32_t nk[4][2];
  for (int n = 0; n < 4; ++n){
    uint32_t a0, a1, b0, b1;
    h_threefry2x32(ck0, ck1, 0u, 0u, &a0, &a1);  // new key
    h_threefry2x32(ck0, ck1, 0u, 1u, &b0, &b1);  // nk
    nk[n][0] = b0; nk[n][1] = b1;
    ck0 = a0; ck1 = a1;
  }

  const int nblocks = (C_DIM * TOUT) / PPB;      // 1600, exact

  if (ws_size >= (size_t)WS_NEEDED){
    uint2*  wsq = (uint2*)d_ws;
    float4* rT  = (float4*)((char*)d_ws + RT_OFF);
    hipLaunchKernelGGL(dac_prepass, dim3((C_DIM * WSROW) / 256), dim3(256),
                       0, stream, x, wsq);
    hipLaunchKernelGGL(r_prepass, dim3((C_DIM * KW + 255) / 256), dim3(256),
                       0, stream, r, rT);
    hipLaunchKernelGGL((memristor_main<true>), dim3(nblocks), dim3(TPB), 0, stream,
                       x, poly_low, poly_high, r, bias, wsq, rT, out,
                       nk[0][0], nk[0][1], nk[1][0], nk[1][1],
                       nk[2][0], nk[2][1], nk[3][0], nk[3][1]);
  } else {
    hipLaunchKernelGGL((memristor_main<false>), dim3(nblocks), dim3(TPB), 0, stream,
                       x, poly_low, poly_high, r, bias,
                       (const uint2*)nullptr, (const float4*)nullptr, out,
                       nk[0][0], nk[0][1], nk[1][0], nk[1][1],
                       nk[2][0], nk[2][1], nk[3][0], nk[3][1]);
  }
}